// Round 8
// baseline (195.688 us; speedup 1.0000x reference)
//
#include <hip/hip_runtime.h>
#include <hip/hip_bf16.h>
#include <math.h>

#define NHEADS 16
#define DKH 64
#define SEQ 2048
#define DMODEL 1024

typedef __attribute__((ext_vector_type(8))) short short8;
typedef __attribute__((ext_vector_type(4))) float f32x4;

// async global->LDS, 16B per lane. LDS dest = wave-uniform base + lane*16.
#define GLDS16(g, l)                                         \
  __builtin_amdgcn_global_load_lds(                          \
      (__attribute__((address_space(1))) void*)(void*)(g),   \
      (__attribute__((address_space(3))) void*)(l), 16, 0, 0)

__device__ __forceinline__ short f2bf(float f) {
  unsigned u = __float_as_uint(f);
  unsigned r = (u + 0x7fffu + ((u >> 16) & 1u)) >> 16;
  return (short)r;
}

// packed f32x2 -> bf16x2 in one instruction (RNE on gfx950; T12 recipe).
__device__ __forceinline__ unsigned cvtpk(float lo, float hi) {
  unsigned r;
  asm("v_cvt_pk_bf16_f32 %0, %1, %2" : "=v"(r) : "v"(lo), "v"(hi));
  return r;
}

__device__ __forceinline__ short8 pack8(float4 a, float4 b) {
  short8 v;
  v[0] = f2bf(a.x); v[1] = f2bf(a.y); v[2] = f2bf(a.z); v[3] = f2bf(a.w);
  v[4] = f2bf(b.x); v[5] = f2bf(b.y); v[6] = f2bf(b.z); v[7] = f2bf(b.w);
  return v;
}

// Swizzled LDS tile [rows][64] bf16. Granule = 8 elems (16B).
// Slot gs of row r holds global granule gs ^ (r&7).
__device__ __forceinline__ int swz(int r, int gran) {
  return r * 64 + ((gran ^ (r & 7)) << 3);
}

// ---------------- precast fp32 -> bf16 + RoPE table (merged) ----------------
__global__ __launch_bounds__(256) void precast_rope_kernel(
    const float* __restrict__ X, const float* __restrict__ Wq,
    const float* __restrict__ Wk, const float* __restrict__ Wv,
    const float* __restrict__ Wo, const int* __restrict__ tp,
    short* __restrict__ Xb, short* __restrict__ Wqb, short* __restrict__ Wkb,
    short* __restrict__ Wvb, short* __restrict__ Wob,
    float* __restrict__ ct, float* __restrict__ st) {
  int bid = blockIdx.x;
  if (bid < 4096) {
    int i = bid * 256 + threadIdx.x;
    const float* src; short* dst; int off;
    if (i < 524288) { src = X; dst = Xb; off = i; }
    else {
      int k = i - 524288; int w = k >> 17; off = k & 131071;
      src = (w == 0) ? Wq : (w == 1) ? Wk : (w == 2) ? Wv : Wo;
      dst = (w == 0) ? Wqb : (w == 1) ? Wkb : (w == 2) ? Wvb : Wob;
    }
    const float4* p = reinterpret_cast<const float4*>(src) + 2 * (size_t)off;
    float4 a = p[0], b = p[1];
    reinterpret_cast<short8*>(dst)[off] = pack8(a, b);
  } else {
    int idx = (bid - 4096) * 256 + threadIdx.x;
    if (idx >= SEQ * 32) return;
    int s = idx >> 5, i = idx & 31;
    int is64 = (tp[1] == 0);
    int p = is64 ? tp[2 * s] : tp[s];
    float invf = powf(10000.0f, -(2.0f * (float)i) / 64.0f);
    float a = (float)p * invf;
    ct[idx] = cosf(a);
    st[idx] = sinf(a);
  }
}

// ---------------- fused QKV projection + RoPE (round-0 verbatim) ------------
// REVERTED to the best-measured structure (51.4 us): 128x128 tile, 4 waves
// 2x2, single-buffered LDS, 2-barrier K-loop, grid 32x24 -> 3 blocks/CU.
// Four schedule variants (8-phase, 256-tile, counted-vmcnt TLP) all landed
// 51-68 us with MfmaUtil<19% -- limiter is shape-structural, not schedule.
// Q,K stored (B,H,S,64) with RoPE applied; V stored TRANSPOSED (B,H,64,S).
__global__ __launch_bounds__(256) void gemm_qkv_kernel(
    const short* __restrict__ X, const short* __restrict__ Wq,
    const short* __restrict__ Wk, const short* __restrict__ Wv,
    short* __restrict__ Qb, short* __restrict__ Kb, short* __restrict__ Vb,
    const float* __restrict__ ct, const float* __restrict__ st) {
  __shared__ __align__(16) short As[128 * 64];
  __shared__ __align__(16) short Bs[128 * 64];
  const int tm = blockIdx.x;          // 32 (M tiles of 128)
  const int tn = blockIdx.y;          // 24 (N tiles of 128 across 3 matrices)
  const int tid = threadIdx.x;
  const int wave = tid >> 6, lane = tid & 63;
  const int l15 = lane & 15, quad = lane >> 4;
  const int wm = wave >> 1, wn = wave & 1;   // 2x2 wave grid, 64x64 each

  const int mid = tn >> 3;             // 0=Q 1=K 2=V
  const int n0 = (tn & 7) * 128;
  const short* W = (mid == 0) ? Wq : (mid == 1 ? Wk : Wv);
  const short* Abase = X + (size_t)(tm * 128) * DMODEL;
  const short* Bbase = W + (size_t)n0 * DMODEL;

  const int lr = lane >> 3;            // row within 8-row chunk
  const int lc = (lane & 7) ^ lr;      // XOR-permuted source granule

  f32x4 acc[4][4];
#pragma unroll
  for (int mb = 0; mb < 4; mb++)
#pragma unroll
    for (int nb = 0; nb < 4; nb++) acc[mb][nb] = (f32x4){0.f, 0.f, 0.f, 0.f};

  for (int kk = 0; kk < 16; kk++) {
    const short* Ak = Abase + kk * 64;
    const short* Bk = Bbase + kk * 64;
#pragma unroll
    for (int i = 0; i < 4; i++) {
      int R = i * 32 + wave * 8;
      GLDS16(Ak + (size_t)(R + lr) * DMODEL + lc * 8, &As[R * 64 + lane * 8]);
    }
#pragma unroll
    for (int i = 0; i < 4; i++) {
      int R = i * 32 + wave * 8;
      GLDS16(Bk + (size_t)(R + lr) * DMODEL + lc * 8, &Bs[R * 64 + lane * 8]);
    }
    __syncthreads();   // drains vmcnt(0): GLDS complete
#pragma unroll
    for (int kg = 0; kg < 2; kg++) {
      short8 af[4], bf[4];
#pragma unroll
      for (int mb = 0; mb < 4; mb++) {
        int r = wm * 64 + mb * 16 + l15;
        af[mb] = *reinterpret_cast<const short8*>(&As[swz(r, kg * 4 + quad)]);
      }
#pragma unroll
      for (int nb = 0; nb < 4; nb++) {
        int r = wn * 64 + nb * 16 + l15;
        bf[nb] = *reinterpret_cast<const short8*>(&Bs[swz(r, kg * 4 + quad)]);
      }
#pragma unroll
      for (int mb = 0; mb < 4; mb++)
#pragma unroll
        for (int nb = 0; nb < 4; nb++)
          acc[mb][nb] = __builtin_amdgcn_mfma_f32_16x16x32_bf16(af[mb], bf[nb], acc[mb][nb], 0, 0, 0);
    }
    __syncthreads();
  }

  // epilogue
#pragma unroll
  for (int mb = 0; mb < 4; mb++) {
    const int s0g = tm * 128 + wm * 64 + mb * 16 + quad * 4;   // rows s0g..s0g+3
    const int b = s0g >> 11, s = s0g & 2047;
#pragma unroll
    for (int nb = 0; nb < 4; nb++) {
      int nl = n0 + wn * 64 + nb * 16 + l15;
      int h = nl >> 6, dd = nl & 63;
      if (mid == 2) {
        // V: packed b64 transposed store -> Vb[(b,h)][dd][s..s+3]
        unsigned u0 = (unsigned)(unsigned short)f2bf(acc[mb][nb][0]) |
                      ((unsigned)(unsigned short)f2bf(acc[mb][nb][1]) << 16);
        unsigned u1 = (unsigned)(unsigned short)f2bf(acc[mb][nb][2]) |
                      ((unsigned)(unsigned short)f2bf(acc[mb][nb][3]) << 16);
        uint2 pk; pk.x = u0; pk.y = u1;
        *reinterpret_cast<uint2*>(Vb + ((size_t)(b * NHEADS + h) * DKH + dd) * SEQ + s) = pk;
      } else {
#pragma unroll
        for (int reg = 0; reg < 4; reg++) {
          float v = acc[mb][nb][reg];
          float pv = __shfl_xor(v, 1);
          int fi = dd >> 1;
          int sg = s + reg;
          float c = ct[sg * 32 + fi], sn = st[sg * 32 + fi];
          float o = (dd & 1) ? (pv * sn + v * c) : (v * c - pv * sn);
          size_t oi = (((size_t)(b * NHEADS + h)) * SEQ + sg) * DKH + dd;
          ((mid == 0) ? Qb : Kb)[oi] = f2bf(o);
        }
      }
    }
  }
}

// ---------------- flash attention (causal), round 16 ------------------------
// QBLK 64 -> 128: attn is LDS-READ-BW bound (each wave reads the whole K/V
// tile per kt regardless of schedule: ~5.8MB/CU total -> ~28us floor at
// QBLK=64). Doubling q-rows per block halves LDS bytes per FLOP: K-frags and
// V-frags are read ONCE per wave and feed BOTH 16-row groups' MFMAs.
// Grid 512 = 8 XCD x 32 CU x 2 rounds; bh = x8*4+(c>>4)*2+r keeps 4 bh/XCD
// (L2-local); qt = r? 15-(c&15) : (c&15) -> per-CU tile count 34, constant.
// Causal: tiles kt >= 2qt get rrel-based masking (rows under a fully-masked
// tile contribute exactly 0 -> exactness preserved). Zero-shuffle PV with
// sigma-staged V kept. __launch_bounds__(256,2): VGPR up to 256, 2 blocks/CU.
__global__ __launch_bounds__(256, 2) void attn_kernel(
    const short* __restrict__ Qb, const short* __restrict__ Kb,
    const short* __restrict__ Vtb, short* __restrict__ Ob) {
  __shared__ __align__(16) short Ks[2][64 * 64];   // [key][d]
  __shared__ __align__(16) short Vs[2][64 * 64];   // [dv][sigma-key]

  const int id = blockIdx.x;           // 512
  const int x8 = id & 7;               // XCD slot (round-robin dispatch)
  const int c  = (id >> 3) & 31;       // CU slot within XCD
  const int rr = id >> 8;              // co-residency round (0..1)
  const int bh = x8 * 4 + (c >> 4) * 2 + rr;       // 4 bh per XCD
  const int qt = rr ? (15 - (c & 15)) : (c & 15);  // per-CU sum const
  const int ntiles = 2 * qt + 2;

  const int tid = threadIdx.x;
  const int wave = tid >> 6, lane = tid & 63;
  const int l15 = lane & 15, quad = lane >> 4;
  const int sr0 = tid >> 3, sc = tid & 7;

  // sigma staging constants for V (per-thread):
  const int vga = ((sc >> 2) << 2) + ((sc & 1) << 1);  // 4m + 2p
  const int vh4 = ((sc >> 1) & 1) * 4;                 // slot-half (shorts)

  const short* Qp = Qb + (size_t)bh * SEQ * DKH;
  const short* Kp = Kb + (size_t)bh * SEQ * DKH;
  const short* Vp = Vtb + (size_t)bh * DKH * SEQ;  // rows = dv, cols = s

  uint4 kreg[2], vreg[2];
#pragma unroll
  for (int i = 0; i < 2; i++) {
    int r = sr0 + i * 32;
    kreg[i] = *reinterpret_cast<const uint4*>(Kp + (size_t)r * DKH + sc * 8);
    vreg[i] = *reinterpret_cast<const uint4*>(Vp + (size_t)r * SEQ + sc * 8);
  }
  // Q fragments: 2 groups x 2 halves, per-lane direct global load.
  short8 qf[2][2];
#pragma unroll
  for (int g = 0; g < 2; g++) {
    const short* qrow = Qp + (size_t)(qt * 128 + wave * 32 + g * 16 + l15) * DKH;
    qf[g][0] = *reinterpret_cast<const short8*>(qrow + quad * 8);
    qf[g][1] = *reinterpret_cast<const short8*>(qrow + (4 + quad) * 8);
  }
#pragma unroll
  for (int i = 0; i < 2; i++) {
    int r = sr0 + i * 32;
    *reinterpret_cast<uint4*>(&Ks[0][swz(r, sc)]) = kreg[i];
    uint2 lo, hi;
    lo.x = vreg[i].x; lo.y = vreg[i].y; hi.x = vreg[i].z; hi.y = vreg[i].w;
    *reinterpret_cast<uint2*>(&Vs[0][swz(r, vga) + vh4]) = lo;
    *reinterpret_cast<uint2*>(&Vs[0][swz(r, vga + 1) + vh4]) = hi;
  }
  __syncthreads();

  f32x4 accO[2][4];
#pragma unroll
  for (int g = 0; g < 2; g++)
#pragma unroll
    for (int i = 0; i < 4; i++) accO[g][i] = (f32x4){0.f, 0.f, 0.f, 0.f};
  float rs[2] = {0.f, 0.f};

  const float SCL = 0.125f * 1.44269504089f;   // 1/sqrt(64) * log2(e)
  const float FM = 13.0f;                      // fixed softmax shift (exact)

  int buf = 0;
  for (int kt = 0; kt < ntiles; kt++) {
    if (kt + 1 < ntiles) {
#pragma unroll
      for (int i = 0; i < 2; i++) {
        int r = sr0 + i * 32;
        kreg[i] = *reinterpret_cast<const uint4*>(Kp + (size_t)((kt + 1) * 64 + r) * DKH + sc * 8);
        vreg[i] = *reinterpret_cast<const uint4*>(Vp + (size_t)r * SEQ + (kt + 1) * 64 + sc * 8);
      }
    }

    // S^T = K Q^T for both row groups; K-frags read ONCE, shared.
    f32x4 sa[2][4];
    __builtin_amdgcn_s_setprio(1);
#pragma unroll
    for (int nb = 0; nb < 4; nb++) {
      int r = nb * 16 + l15;
      short8 kf0 = *reinterpret_cast<const short8*>(&Ks[buf][swz(r, quad)]);
      short8 kf1 = *reinterpret_cast<const short8*>(&Ks[buf][swz(r, 4 + quad)]);
      sa[0][nb] = (f32x4){0.f, 0.f, 0.f, 0.f};
      sa[0][nb] = __builtin_amdgcn_mfma_f32_16x16x32_bf16(kf0, qf[0][0], sa[0][nb], 0, 0, 0);
      sa[0][nb] = __builtin_amdgcn_mfma_f32_16x16x32_bf16(kf1, qf[0][1], sa[0][nb], 0, 0, 0);
      sa[1][nb] = (f32x4){0.f, 0.f, 0.f, 0.f};
      sa[1][nb] = __builtin_amdgcn_mfma_f32_16x16x32_bf16(kf0, qf[1][0], sa[1][nb], 0, 0, 0);
      sa[1][nb] = __builtin_amdgcn_mfma_f32_16x16x32_bf16(kf1, qf[1][1], sa[1][nb], 0, 0, 0);
    }
    __builtin_amdgcn_s_setprio(0);

    const bool diag = (kt >= 2 * qt);
    unsigned pu[2][4], pw[2][4];
#pragma unroll
    for (int g = 0; g < 2; g++) {
      const int rrel = qt * 128 + wave * 32 + g * 16 + l15 - kt * 64;
#pragma unroll
      for (int nb = 0; nb < 4; nb++) {
        float p0 = exp2f(sa[g][nb][0] * SCL - FM);
        float p1 = exp2f(sa[g][nb][1] * SCL - FM);
        float p2 = exp2f(sa[g][nb][2] * SCL - FM);
        float p3 = exp2f(sa[g][nb][3] * SCL - FM);
        if (diag) {
          int kbase = nb * 16 + quad * 4;
          if (kbase + 0 > rrel) p0 = 0.f;
          if (kbase + 1 > rrel) p1 = 0.f;
          if (kbase + 2 > rrel) p2 = 0.f;
          if (kbase + 3 > rrel) p3 = 0.f;
        }
        rs[g] += (p0 + p1) + (p2 + p3);
        pu[g][nb] = cvtpk(p0, p1);
        pw[g][nb] = cvtpk(p2, p3);
      }
    }

    // O += P V, zero-shuffle; V-frags read ONCE, shared across groups.
    short8 pf[2][2];
#pragma unroll
    for (int g = 0; g < 2; g++) {
      unsigned* w0 = reinterpret_cast<unsigned*>(&pf[g][0]);
      w0[0] = pu[g][0]; w0[1] = pw[g][0]; w0[2] = pu[g][1]; w0[3] = pw[g][1];
      unsigned* w1 = reinterpret_cast<unsigned*>(&pf[g][1]);
      w1[0] = pu[g][2]; w1[1] = pw[g][2]; w1[2] = pu[g][3]; w1[3] = pw[g][3];
    }
    __builtin_amdgcn_s_setprio(1);
#pragma unroll
    for (int db = 0; db < 4; db++) {
      int dv = db * 16 + l15;
      short8 vf0 = *reinterpret_cast<const short8*>(&Vs[buf][swz(dv, quad)]);
      short8 vf1 = *reinterpret_cast<const short8*>(&Vs[buf][swz(dv, 4 + quad)]);
      accO[0][db] = __builtin_amdgcn_mfma_f32_16x16x32_bf16(pf[0][0], vf0, accO[0][db], 0, 0, 0);
      accO[0][db] = __builtin_amdgcn_mfma_f32_16x16x32_bf16(pf[0][1], vf1, accO[0][db], 0, 0, 0);
      accO[1][db] = __builtin_amdgcn_mfma_f32_16x16x32_bf16(pf[1][0], vf0, accO[1][db], 0, 0, 0);
      accO[1][db] = __builtin_amdgcn_mfma_f32_16x16x32_bf16(pf[1][1], vf1, accO[1][db], 0, 0, 0);
    }
    __builtin_amdgcn_s_setprio(0);

    if (kt + 1 < ntiles) {
      int nbuf = buf ^ 1;
#pragma unroll
      for (int i = 0; i < 2; i++) {
        int r = sr0 + i * 32;
        *reinterpret_cast<uint4*>(&Ks[nbuf][swz(r, sc)]) = kreg[i];
        uint2 lo, hi;
        lo.x = vreg[i].x; lo.y = vreg[i].y; hi.x = vreg[i].z; hi.y = vreg[i].w;
        *reinterpret_cast<uint2*>(&Vs[nbuf][swz(r, vga) + vh4]) = lo;
        *reinterpret_cast<uint2*>(&Vs[nbuf][swz(r, vga + 1) + vh4]) = hi;
      }
      __syncthreads();
      buf = nbuf;
    }
  }

  // per-group row-sum reduce + output
  int b = bh >> 4, h = bh & 15;
#pragma unroll
  for (int g = 0; g < 2; g++) {
    float t = rs[g];
    t += __shfl_xor(t, 16);
    t += __shfl_xor(t, 32);
    float lv[4];
#pragma unroll
    for (int reg = 0; reg < 4; reg++) lv[reg] = __shfl(t, quad * 4 + reg);
#pragma unroll
    for (int db = 0; db < 4; db++)
#pragma unroll
      for (int reg = 0; reg < 4; reg++) {
        int s = qt * 128 + wave * 32 + g * 16 + quad * 4 + reg;
        int dv = db * 16 + l15;
        float o = accO[g][db][reg] / lv[reg];
        Ob[((size_t)(b * SEQ + s)) * DMODEL + h * DKH + dv] = f2bf(o);
      }
  }
}

// ---------------- output projection, 128x64 tile + GLDS (fp32 output) -------
__global__ __launch_bounds__(256) void gemm_out_kernel(
    const short* __restrict__ X, const short* __restrict__ Wo, float* __restrict__ Out) {
  __shared__ __align__(16) short As[128 * 64];
  __shared__ __align__(16) short Bs[64 * 64];
  const int tm = blockIdx.x;   // 32 (M tiles of 128)
  const int tn = blockIdx.y;   // 16 (N tiles of 64)
  const int tid = threadIdx.x;
  const int wave = tid >> 6, lane = tid & 63;
  const int l15 = lane & 15, quad = lane >> 4;
  const int wm = wave >> 1, wn = wave & 1;   // wave tile 64M x 32N

  const short* Abase = X + (size_t)(tm * 128) * DMODEL;
  const short* Bbase = Wo + (size_t)(tn * 64) * DMODEL;

  const int lr = lane >> 3;
  const int lc = (lane & 7) ^ lr;

  f32x4 acc[4][2];
#pragma unroll
  for (int mb = 0; mb < 4; mb++)
#pragma unroll
    for (int nb = 0; nb < 2; nb++) acc[mb][nb] = (f32x4){0.f, 0.f, 0.f, 0.f};

  for (int kk = 0; kk < 16; kk++) {
    const short* Ak = Abase + kk * 64;
    const short* Bk = Bbase + kk * 64;
#pragma unroll
    for (int i = 0; i < 4; i++) {
      int R = i * 32 + wave * 8;
      GLDS16(Ak + (size_t)(R + lr) * DMODEL + lc * 8, &As[R * 64 + lane * 8]);
    }
#pragma unroll
    for (int i = 0; i < 2; i++) {
      int R = i * 32 + wave * 8;
      GLDS16(Bk + (size_t)(R + lr) * DMODEL + lc * 8, &Bs[R * 64 + lane * 8]);
    }
    __syncthreads();
#pragma unroll
    for (int kg = 0; kg < 2; kg++) {
      short8 af[4], bf[2];
#pragma unroll
      for (int mb = 0; mb < 4; mb++) {
        int r = wm * 64 + mb * 16 + l15;
        af[mb] = *reinterpret_cast<const short8*>(&As[swz(r, kg * 4 + quad)]);
      }
#pragma unroll
      for (int nb = 0; nb < 2; nb++) {
        int r = wn * 32 + nb * 16 + l15;
        bf[nb] = *reinterpret_cast<const short8*>(&Bs[swz(r, kg * 4 + quad)]);
      }
#pragma unroll
      for (int mb = 0; mb < 4; mb++)
#pragma unroll
        for (int nb = 0; nb < 2; nb++)
          acc[mb][nb] = __builtin_amdgcn_mfma_f32_16x16x32_bf16(af[mb], bf[nb], acc[mb][nb], 0, 0, 0);
    }
    __syncthreads();
  }
#pragma unroll
  for (int mb = 0; mb < 4; mb++)
#pragma unroll
    for (int nb = 0; nb < 2; nb++)
#pragma unroll
      for (int reg = 0; reg < 4; reg++) {
        int rg = tm * 128 + wm * 64 + mb * 16 + quad * 4 + reg;
        int col = tn * 64 + wn * 32 + nb * 16 + l15;
        Out[(size_t)rg * DMODEL + col] = acc[mb][nb][reg];
      }
}

extern "C" void kernel_launch(void* const* d_in, const int* in_sizes, int n_in,
                              void* d_out, int out_size, void* d_ws, size_t ws_size,
                              hipStream_t stream) {
  (void)in_sizes; (void)n_in; (void)out_size; (void)ws_size;
  const float* X  = (const float*)d_in[0];
  const int*   tp = (const int*)d_in[1];
  const float* Wq = (const float*)d_in[2];
  const float* Wk = (const float*)d_in[3];
  const float* Wv = (const float*)d_in[4];
  const float* Wo = (const float*)d_in[5];
  float* Out = (float*)d_out;

  short* Qb  = (short*)d_ws;           // 4M shorts each
  short* Kb  = Qb + 4194304;
  short* Vb  = Kb + 4194304;           // holds V^T (B,H,D,S)
  short* Ab  = Vb + 4194304;
  short* Xb  = Ab + 4194304;           // 4M
  short* Wqb = Xb + 4194304;           // 1M each
  short* Wkb = Wqb + 1048576;
  short* Wvb = Wkb + 1048576;
  short* Wob = Wvb + 1048576;
  float* ct  = (float*)(Wob + 1048576);
  float* st  = ct + SEQ * 32;

  precast_rope_kernel<<<dim3(4352), dim3(256), 0, stream>>>(
      X, Wq, Wk, Wv, Wo, tp, Xb, Wqb, Wkb, Wvb, Wob, ct, st);
  gemm_qkv_kernel<<<dim3(32, 24), dim3(256), 0, stream>>>(Xb, Wqb, Wkb, Wvb,
                                                          Qb, Kb, Vb, ct, st);
  attn_kernel<<<dim3(512), dim3(256), 0, stream>>>(Qb, Kb, Vb, Ab);
  gemm_out_kernel<<<dim3(32, 16), dim3(256), 0, stream>>>(Ab, Wob, Out);
}

// Round 9
// 186.291 us; speedup vs baseline: 1.0504x; 1.0504x over previous
//
#include <hip/hip_runtime.h>
#include <hip/hip_bf16.h>
#include <math.h>

#define NHEADS 16
#define DKH 64
#define SEQ 2048
#define DMODEL 1024

typedef __attribute__((ext_vector_type(8))) short short8;
typedef __attribute__((ext_vector_type(4))) float f32x4;

// async global->LDS, 16B per lane. LDS dest = wave-uniform base + lane*16.
#define GLDS16(g, l)                                         \
  __builtin_amdgcn_global_load_lds(                          \
      (__attribute__((address_space(1))) void*)(void*)(g),   \
      (__attribute__((address_space(3))) void*)(l), 16, 0, 0)

__device__ __forceinline__ short f2bf(float f) {
  unsigned u = __float_as_uint(f);
  unsigned r = (u + 0x7fffu + ((u >> 16) & 1u)) >> 16;
  return (short)r;
}

// packed f32x2 -> bf16x2 in one instruction (RNE on gfx950; T12 recipe).
__device__ __forceinline__ unsigned cvtpk(float lo, float hi) {
  unsigned r;
  asm("v_cvt_pk_bf16_f32 %0, %1, %2" : "=v"(r) : "v"(lo), "v"(hi));
  return r;
}

__device__ __forceinline__ short8 pack8(float4 a, float4 b) {
  short8 v;
  v[0] = f2bf(a.x); v[1] = f2bf(a.y); v[2] = f2bf(a.z); v[3] = f2bf(a.w);
  v[4] = f2bf(b.x); v[5] = f2bf(b.y); v[6] = f2bf(b.z); v[7] = f2bf(b.w);
  return v;
}

// Swizzled LDS tile [rows][64] bf16. Granule = 8 elems (16B).
// Slot gs of row r holds global granule gs ^ (r&7).
__device__ __forceinline__ int swz(int r, int gran) {
  return r * 64 + ((gran ^ (r & 7)) << 3);
}

// ---------------- precast fp32 -> bf16 + RoPE table (merged) ----------------
__global__ __launch_bounds__(256) void precast_rope_kernel(
    const float* __restrict__ X, const float* __restrict__ Wq,
    const float* __restrict__ Wk, const float* __restrict__ Wv,
    const float* __restrict__ Wo, const int* __restrict__ tp,
    short* __restrict__ Xb, short* __restrict__ Wqb, short* __restrict__ Wkb,
    short* __restrict__ Wvb, short* __restrict__ Wob,
    float* __restrict__ ct, float* __restrict__ st) {
  int bid = blockIdx.x;
  if (bid < 4096) {
    int i = bid * 256 + threadIdx.x;
    const float* src; short* dst; int off;
    if (i < 524288) { src = X; dst = Xb; off = i; }
    else {
      int k = i - 524288; int w = k >> 17; off = k & 131071;
      src = (w == 0) ? Wq : (w == 1) ? Wk : (w == 2) ? Wv : Wo;
      dst = (w == 0) ? Wqb : (w == 1) ? Wkb : (w == 2) ? Wvb : Wob;
    }
    const float4* p = reinterpret_cast<const float4*>(src) + 2 * (size_t)off;
    float4 a = p[0], b = p[1];
    reinterpret_cast<short8*>(dst)[off] = pack8(a, b);
  } else {
    int idx = (bid - 4096) * 256 + threadIdx.x;
    if (idx >= SEQ * 32) return;
    int s = idx >> 5, i = idx & 31;
    int is64 = (tp[1] == 0);
    int p = is64 ? tp[2 * s] : tp[s];
    float invf = powf(10000.0f, -(2.0f * (float)i) / 64.0f);
    float a = (float)p * invf;
    ct[idx] = cosf(a);
    st[idx] = sinf(a);
  }
}

// ---------------- fused QKV projection + RoPE (round-0 verbatim) ------------
// Best-measured structure (51.4 us): 128x128 tile, 4 waves 2x2, single-
// buffered LDS, 2-barrier K-loop, grid 32x24 -> 3 blocks/CU. DECLARED DONE.
// Q,K stored (B,H,S,64) with RoPE applied; V stored TRANSPOSED (B,H,64,S).
__global__ __launch_bounds__(256) void gemm_qkv_kernel(
    const short* __restrict__ X, const short* __restrict__ Wq,
    const short* __restrict__ Wk, const short* __restrict__ Wv,
    short* __restrict__ Qb, short* __restrict__ Kb, short* __restrict__ Vb,
    const float* __restrict__ ct, const float* __restrict__ st) {
  __shared__ __align__(16) short As[128 * 64];
  __shared__ __align__(16) short Bs[128 * 64];
  const int tm = blockIdx.x;          // 32 (M tiles of 128)
  const int tn = blockIdx.y;          // 24 (N tiles of 128 across 3 matrices)
  const int tid = threadIdx.x;
  const int wave = tid >> 6, lane = tid & 63;
  const int l15 = lane & 15, quad = lane >> 4;
  const int wm = wave >> 1, wn = wave & 1;   // 2x2 wave grid, 64x64 each

  const int mid = tn >> 3;             // 0=Q 1=K 2=V
  const int n0 = (tn & 7) * 128;
  const short* W = (mid == 0) ? Wq : (mid == 1 ? Wk : Wv);
  const short* Abase = X + (size_t)(tm * 128) * DMODEL;
  const short* Bbase = W + (size_t)n0 * DMODEL;

  const int lr = lane >> 3;            // row within 8-row chunk
  const int lc = (lane & 7) ^ lr;      // XOR-permuted source granule

  f32x4 acc[4][4];
#pragma unroll
  for (int mb = 0; mb < 4; mb++)
#pragma unroll
    for (int nb = 0; nb < 4; nb++) acc[mb][nb] = (f32x4){0.f, 0.f, 0.f, 0.f};

  for (int kk = 0; kk < 16; kk++) {
    const short* Ak = Abase + kk * 64;
    const short* Bk = Bbase + kk * 64;
#pragma unroll
    for (int i = 0; i < 4; i++) {
      int R = i * 32 + wave * 8;
      GLDS16(Ak + (size_t)(R + lr) * DMODEL + lc * 8, &As[R * 64 + lane * 8]);
    }
#pragma unroll
    for (int i = 0; i < 4; i++) {
      int R = i * 32 + wave * 8;
      GLDS16(Bk + (size_t)(R + lr) * DMODEL + lc * 8, &Bs[R * 64 + lane * 8]);
    }
    __syncthreads();   // drains vmcnt(0): GLDS complete
#pragma unroll
    for (int kg = 0; kg < 2; kg++) {
      short8 af[4], bf[4];
#pragma unroll
      for (int mb = 0; mb < 4; mb++) {
        int r = wm * 64 + mb * 16 + l15;
        af[mb] = *reinterpret_cast<const short8*>(&As[swz(r, kg * 4 + quad)]);
      }
#pragma unroll
      for (int nb = 0; nb < 4; nb++) {
        int r = wn * 64 + nb * 16 + l15;
        bf[nb] = *reinterpret_cast<const short8*>(&Bs[swz(r, kg * 4 + quad)]);
      }
#pragma unroll
      for (int mb = 0; mb < 4; mb++)
#pragma unroll
        for (int nb = 0; nb < 4; nb++)
          acc[mb][nb] = __builtin_amdgcn_mfma_f32_16x16x32_bf16(af[mb], bf[nb], acc[mb][nb], 0, 0, 0);
    }
    __syncthreads();
  }

  // epilogue
#pragma unroll
  for (int mb = 0; mb < 4; mb++) {
    const int s0g = tm * 128 + wm * 64 + mb * 16 + quad * 4;   // rows s0g..s0g+3
    const int b = s0g >> 11, s = s0g & 2047;
#pragma unroll
    for (int nb = 0; nb < 4; nb++) {
      int nl = n0 + wn * 64 + nb * 16 + l15;
      int h = nl >> 6, dd = nl & 63;
      if (mid == 2) {
        // V: packed b64 transposed store -> Vb[(b,h)][dd][s..s+3]
        unsigned u0 = (unsigned)(unsigned short)f2bf(acc[mb][nb][0]) |
                      ((unsigned)(unsigned short)f2bf(acc[mb][nb][1]) << 16);
        unsigned u1 = (unsigned)(unsigned short)f2bf(acc[mb][nb][2]) |
                      ((unsigned)(unsigned short)f2bf(acc[mb][nb][3]) << 16);
        uint2 pk; pk.x = u0; pk.y = u1;
        *reinterpret_cast<uint2*>(Vb + ((size_t)(b * NHEADS + h) * DKH + dd) * SEQ + s) = pk;
      } else {
#pragma unroll
        for (int reg = 0; reg < 4; reg++) {
          float v = acc[mb][nb][reg];
          float pv = __shfl_xor(v, 1);
          int fi = dd >> 1;
          int sg = s + reg;
          float c = ct[sg * 32 + fi], sn = st[sg * 32 + fi];
          float o = (dd & 1) ? (pv * sn + v * c) : (v * c - pv * sn);
          size_t oi = (((size_t)(b * NHEADS + h)) * SEQ + sg) * DKH + dd;
          ((mid == 0) ? Qb : Kb)[oi] = f2bf(o);
        }
      }
    }
  }
}

// ---------------- flash attention (causal), round-6 source restored ---------
// QBLK=64, 4 blocks/CU (the QBLK=128 variant halved occupancy -> 55us; this
// one inferred ~33us). Zero-shuffle PV with SIGMA-STAGED V: key permutation
// applied at staging, PV V-read is a single ds_read_b128 (conflict-free).
// Balanced qt map + XCD bh grouping + cvt_pk + setprio.
__global__ __launch_bounds__(256, 4) void attn_kernel(
    const short* __restrict__ Qb, const short* __restrict__ Kb,
    const short* __restrict__ Vtb, short* __restrict__ Ob) {
  __shared__ __align__(16) short Ks[2][64 * 64];   // [key][d]
  __shared__ __align__(16) short Vs[2][64 * 64];   // [dv][sigma-key]

  const int id = blockIdx.x;
  const int x8 = id & 7;               // XCD slot (round-robin dispatch)
  const int c  = (id >> 3) & 31;       // CU slot within XCD
  const int q2 = id >> 8;              // co-residency round (0..3)
  const int bh = x8 * 4 + q2;          // 4 consecutive bh per XCD (L2 local)
  const int qt = (q2 == 0) ? c
               : (q2 == 1) ? (31 - c)
               : (q2 == 2) ? ((c + 16) & 31)
               : ((15 - c) & 31);      // per-CU qt sum = 62 for all c

  const int tid = threadIdx.x;
  const int wave = tid >> 6, lane = tid & 63;
  const int l15 = lane & 15, quad = lane >> 4;
  const int sr0 = tid >> 3, sc = tid & 7;

  // sigma staging constants for V (per-thread):
  const int vga = ((sc >> 2) << 2) + ((sc & 1) << 1);  // 4m + 2p
  const int vh4 = ((sc >> 1) & 1) * 4;                 // slot-half (shorts)

  const short* Qp = Qb + (size_t)bh * SEQ * DKH;
  const short* Kp = Kb + (size_t)bh * SEQ * DKH;
  const short* Vp = Vtb + (size_t)bh * DKH * SEQ;  // rows = dv, cols = s

  uint4 kreg[2], vreg[2];
#pragma unroll
  for (int i = 0; i < 2; i++) {
    int r = sr0 + i * 32;
    kreg[i] = *reinterpret_cast<const uint4*>(Kp + (size_t)r * DKH + sc * 8);
    vreg[i] = *reinterpret_cast<const uint4*>(Vp + (size_t)r * SEQ + sc * 8);
  }
  // Q fragments: per-lane direct global load (row qt*64+wave*16+l15).
  short8 qf0, qf1;
  {
    const short* qrow = Qp + (size_t)(qt * 64 + wave * 16 + l15) * DKH;
    qf0 = *reinterpret_cast<const short8*>(qrow + quad * 8);
    qf1 = *reinterpret_cast<const short8*>(qrow + (4 + quad) * 8);
  }
#pragma unroll
  for (int i = 0; i < 2; i++) {
    int r = sr0 + i * 32;
    *reinterpret_cast<uint4*>(&Ks[0][swz(r, sc)]) = kreg[i];
    uint2 lo, hi;
    lo.x = vreg[i].x; lo.y = vreg[i].y; hi.x = vreg[i].z; hi.y = vreg[i].w;
    *reinterpret_cast<uint2*>(&Vs[0][swz(r, vga) + vh4]) = lo;
    *reinterpret_cast<uint2*>(&Vs[0][swz(r, vga + 1) + vh4]) = hi;
  }
  __syncthreads();

  f32x4 accO[4];
#pragma unroll
  for (int i = 0; i < 4; i++) accO[i] = (f32x4){0.f, 0.f, 0.f, 0.f};
  float rs = 0.f;   // partial row-sum for q-row (wave*16+l15), this lane's keys

  const float SCL = 0.125f * 1.44269504089f;   // 1/sqrt(64) * log2(e)
  const float FM = 13.0f;                      // fixed softmax shift (exact)

  int buf = 0;
  for (int kt = 0; kt <= qt; kt++) {
    if (kt < qt) {
#pragma unroll
      for (int i = 0; i < 2; i++) {
        int r = sr0 + i * 32;
        kreg[i] = *reinterpret_cast<const uint4*>(Kp + (size_t)((kt + 1) * 64 + r) * DKH + sc * 8);
        vreg[i] = *reinterpret_cast<const uint4*>(Vp + (size_t)r * SEQ + (kt + 1) * 64 + sc * 8);
      }
    }

    // S^T = K Q^T : D[m=key][n=qrow]; lane holds keys nb*16+quad*4+{0..3},
    // q-row = wave*16+l15.
    f32x4 sa[4];
    __builtin_amdgcn_s_setprio(1);
#pragma unroll
    for (int nb = 0; nb < 4; nb++) {
      sa[nb] = (f32x4){0.f, 0.f, 0.f, 0.f};
      int r = nb * 16 + l15;
      short8 kf0 = *reinterpret_cast<const short8*>(&Ks[buf][swz(r, quad)]);
      sa[nb] = __builtin_amdgcn_mfma_f32_16x16x32_bf16(kf0, qf0, sa[nb], 0, 0, 0);
      short8 kf1 = *reinterpret_cast<const short8*>(&Ks[buf][swz(r, 4 + quad)]);
      sa[nb] = __builtin_amdgcn_mfma_f32_16x16x32_bf16(kf1, qf1, sa[nb], 0, 0, 0);
    }
    __builtin_amdgcn_s_setprio(0);

    const bool diag = (kt == qt);
    const int prow = wave * 16 + l15;          // this lane's q-row (P row)
    unsigned pu[4], pw[4];                     // packed P: u=keys 4q+{0,1}, w=+{2,3}
#pragma unroll
    for (int nb = 0; nb < 4; nb++) {
      float p0 = exp2f(sa[nb][0] * SCL - FM);
      float p1 = exp2f(sa[nb][1] * SCL - FM);
      float p2 = exp2f(sa[nb][2] * SCL - FM);
      float p3 = exp2f(sa[nb][3] * SCL - FM);
      if (diag) {
        int kbase = nb * 16 + quad * 4;
        if (kbase + 0 > prow) p0 = 0.f;
        if (kbase + 1 > prow) p1 = 0.f;
        if (kbase + 2 > prow) p2 = 0.f;
        if (kbase + 3 > prow) p3 = 0.f;
      }
      rs += (p0 + p1) + (p2 + p3);
      pu[nb] = cvtpk(p0, p1);
      pw[nb] = cvtpk(p2, p3);
    }

    // O += P V, zero-shuffle: A-frag = packed P as produced (sigma key order);
    // V staged in the SAME sigma order -> single b128 read per fragment at
    // granule quad (keys of nb 0,1) and 4+quad (nb 2,3).
    short8 pf0, pf1;
    {
      unsigned* w0 = reinterpret_cast<unsigned*>(&pf0);
      w0[0] = pu[0]; w0[1] = pw[0]; w0[2] = pu[1]; w0[3] = pw[1];
      unsigned* w1 = reinterpret_cast<unsigned*>(&pf1);
      w1[0] = pu[2]; w1[1] = pw[2]; w1[2] = pu[3]; w1[3] = pw[3];
    }
    __builtin_amdgcn_s_setprio(1);
#pragma unroll
    for (int db = 0; db < 4; db++) {
      int dv = db * 16 + l15;
      short8 vf0 = *reinterpret_cast<const short8*>(&Vs[buf][swz(dv, quad)]);
      accO[db] = __builtin_amdgcn_mfma_f32_16x16x32_bf16(pf0, vf0, accO[db], 0, 0, 0);
      short8 vf1 = *reinterpret_cast<const short8*>(&Vs[buf][swz(dv, 4 + quad)]);
      accO[db] = __builtin_amdgcn_mfma_f32_16x16x32_bf16(pf1, vf1, accO[db], 0, 0, 0);
    }
    __builtin_amdgcn_s_setprio(0);

    if (kt < qt) {
      int nbuf = buf ^ 1;
#pragma unroll
      for (int i = 0; i < 2; i++) {
        int r = sr0 + i * 32;
        *reinterpret_cast<uint4*>(&Ks[nbuf][swz(r, sc)]) = kreg[i];
        uint2 lo, hi;
        lo.x = vreg[i].x; lo.y = vreg[i].y; hi.x = vreg[i].z; hi.y = vreg[i].w;
        *reinterpret_cast<uint2*>(&Vs[nbuf][swz(r, vga) + vh4]) = lo;
        *reinterpret_cast<uint2*>(&Vs[nbuf][swz(r, vga + 1) + vh4]) = hi;
      }
      __syncthreads();
      buf = nbuf;
    }
  }

  // reduce rs across the 4 quads sharing each l15 (full row sum)
  float t = rs;
  t += __shfl_xor(t, 16);
  t += __shfl_xor(t, 32);
  // accO rows are qrow = quad*4+reg; fetch lrow from lane l15 = quad*4+reg
  float lv[4];
#pragma unroll
  for (int reg = 0; reg < 4; reg++) lv[reg] = __shfl(t, quad * 4 + reg);

  // write (B,S,1024) bf16
  int b = bh >> 4, h = bh & 15;
#pragma unroll
  for (int db = 0; db < 4; db++)
#pragma unroll
    for (int reg = 0; reg < 4; reg++) {
      int s = qt * 64 + wave * 16 + quad * 4 + reg;
      int dv = db * 16 + l15;
      float o = accO[db][reg] / lv[reg];
      Ob[((size_t)(b * SEQ + s)) * DMODEL + h * DKH + dv] = f2bf(o);
    }
}

// ---------------- output projection, round 17: BK=128 -----------------------
// Session budget arithmetic says gemm_out has been ~45-55us all along (hidden
// below the top-5 cutoff): its wall time = 16 x (vmcnt(0)-drain + L2 latency)
// per K-step, same as qkv despite 1/3 the FLOPs. Fix: halve the serial
// K-steps -- stage TWO 64-wide K-half-tiles per outer iteration (8 outer
// iters x 12 GLDS/wave; same total bytes, half the drain+barrier events).
// LDS 48 KiB (As 2x16K + Bs 2x8K), grid 512 = 2 blocks/CU.
__global__ __launch_bounds__(256) void gemm_out_kernel(
    const short* __restrict__ X, const short* __restrict__ Wo, float* __restrict__ Out) {
  __shared__ __align__(16) short As[2][128 * 64];
  __shared__ __align__(16) short Bs[2][64 * 64];
  const int tm = blockIdx.x;   // 32 (M tiles of 128)
  const int tn = blockIdx.y;   // 16 (N tiles of 64)
  const int tid = threadIdx.x;
  const int wave = tid >> 6, lane = tid & 63;
  const int l15 = lane & 15, quad = lane >> 4;
  const int wm = wave >> 1, wn = wave & 1;   // wave tile 64M x 32N

  const short* Abase = X + (size_t)(tm * 128) * DMODEL;
  const short* Bbase = Wo + (size_t)(tn * 64) * DMODEL;

  const int lr = lane >> 3;
  const int lc = (lane & 7) ^ lr;

  f32x4 acc[4][2];
#pragma unroll
  for (int mb = 0; mb < 4; mb++)
#pragma unroll
    for (int nb = 0; nb < 2; nb++) acc[mb][nb] = (f32x4){0.f, 0.f, 0.f, 0.f};

  for (int ko = 0; ko < 8; ko++) {   // BK=128: two 64-wide halves per iter
    const short* Ak = Abase + ko * 128;
    const short* Bk = Bbase + ko * 128;
#pragma unroll
    for (int h = 0; h < 2; h++) {
#pragma unroll
      for (int i = 0; i < 4; i++) {
        int R = i * 32 + wave * 8;
        GLDS16(Ak + (size_t)(R + lr) * DMODEL + h * 64 + lc * 8,
               &As[h][R * 64 + lane * 8]);
      }
#pragma unroll
      for (int i = 0; i < 2; i++) {
        int R = i * 32 + wave * 8;
        GLDS16(Bk + (size_t)(R + lr) * DMODEL + h * 64 + lc * 8,
               &Bs[h][R * 64 + lane * 8]);
      }
    }
    __syncthreads();   // one drain per 128 K (was per 64)
#pragma unroll
    for (int h = 0; h < 2; h++) {
#pragma unroll
      for (int kg = 0; kg < 2; kg++) {
        short8 af[4], bf[2];
#pragma unroll
        for (int mb = 0; mb < 4; mb++) {
          int r = wm * 64 + mb * 16 + l15;
          af[mb] = *reinterpret_cast<const short8*>(&As[h][swz(r, kg * 4 + quad)]);
        }
#pragma unroll
        for (int nb = 0; nb < 2; nb++) {
          int r = wn * 32 + nb * 16 + l15;
          bf[nb] = *reinterpret_cast<const short8*>(&Bs[h][swz(r, kg * 4 + quad)]);
        }
#pragma unroll
        for (int mb = 0; mb < 4; mb++)
#pragma unroll
          for (int nb = 0; nb < 2; nb++)
            acc[mb][nb] = __builtin_amdgcn_mfma_f32_16x16x32_bf16(af[mb], bf[nb], acc[mb][nb], 0, 0, 0);
      }
    }
    __syncthreads();
  }
#pragma unroll
  for (int mb = 0; mb < 4; mb++)
#pragma unroll
    for (int nb = 0; nb < 2; nb++)
#pragma unroll
      for (int reg = 0; reg < 4; reg++) {
        int rg = tm * 128 + wm * 64 + mb * 16 + quad * 4 + reg;
        int col = tn * 64 + wn * 32 + nb * 16 + l15;
        Out[(size_t)rg * DMODEL + col] = acc[mb][nb][reg];
      }
}

extern "C" void kernel_launch(void* const* d_in, const int* in_sizes, int n_in,
                              void* d_out, int out_size, void* d_ws, size_t ws_size,
                              hipStream_t stream) {
  (void)in_sizes; (void)n_in; (void)out_size; (void)ws_size;
  const float* X  = (const float*)d_in[0];
  const int*   tp = (const int*)d_in[1];
  const float* Wq = (const float*)d_in[2];
  const float* Wk = (const float*)d_in[3];
  const float* Wv = (const float*)d_in[4];
  const float* Wo = (const float*)d_in[5];
  float* Out = (float*)d_out;

  short* Qb  = (short*)d_ws;           // 4M shorts each
  short* Kb  = Qb + 4194304;
  short* Vb  = Kb + 4194304;           // holds V^T (B,H,D,S)
  short* Ab  = Vb + 4194304;
  short* Xb  = Ab + 4194304;           // 4M
  short* Wqb = Xb + 4194304;           // 1M each
  short* Wkb = Wqb + 1048576;
  short* Wvb = Wkb + 1048576;
  short* Wob = Wvb + 1048576;
  float* ct  = (float*)(Wob + 1048576);
  float* st  = ct + SEQ * 32;

  precast_rope_kernel<<<dim3(4352), dim3(256), 0, stream>>>(
      X, Wq, Wk, Wv, Wo, tp, Xb, Wqb, Wkb, Wvb, Wob, ct, st);
  gemm_qkv_kernel<<<dim3(32, 24), dim3(256), 0, stream>>>(Xb, Wqb, Wkb, Wvb,
                                                          Qb, Kb, Vb, ct, st);
  attn_kernel<<<dim3(1024), dim3(256), 0, stream>>>(Qb, Kb, Vb, Ab);
  gemm_out_kernel<<<dim3(32, 16), dim3(256), 0, stream>>>(Ab, Wob, Out);
}

// Round 10
// 184.714 us; speedup vs baseline: 1.0594x; 1.0085x over previous
//
#include <hip/hip_runtime.h>
#include <hip/hip_bf16.h>
#include <math.h>

#define NHEADS 16
#define DKH 64
#define SEQ 2048
#define DMODEL 1024

typedef __attribute__((ext_vector_type(8))) short short8;
typedef __attribute__((ext_vector_type(4))) float f32x4;

// async global->LDS, 16B per lane. LDS dest = wave-uniform base + lane*16.
#define GLDS16(g, l)                                         \
  __builtin_amdgcn_global_load_lds(                          \
      (__attribute__((address_space(1))) void*)(void*)(g),   \
      (__attribute__((address_space(3))) void*)(l), 16, 0, 0)

__device__ __forceinline__ short f2bf(float f) {
  unsigned u = __float_as_uint(f);
  unsigned r = (u + 0x7fffu + ((u >> 16) & 1u)) >> 16;
  return (short)r;
}

// packed f32x2 -> bf16x2 in one instruction (RNE on gfx950; T12 recipe).
__device__ __forceinline__ unsigned cvtpk(float lo, float hi) {
  unsigned r;
  asm("v_cvt_pk_bf16_f32 %0, %1, %2" : "=v"(r) : "v"(lo), "v"(hi));
  return r;
}

__device__ __forceinline__ short8 pack8(float4 a, float4 b) {
  short8 v;
  v[0] = f2bf(a.x); v[1] = f2bf(a.y); v[2] = f2bf(a.z); v[3] = f2bf(a.w);
  v[4] = f2bf(b.x); v[5] = f2bf(b.y); v[6] = f2bf(b.z); v[7] = f2bf(b.w);
  return v;
}

// Swizzled LDS tile [rows][64] bf16. Granule = 8 elems (16B).
// Slot gs of row r holds global granule gs ^ (r&7).
__device__ __forceinline__ int swz(int r, int gran) {
  return r * 64 + ((gran ^ (r & 7)) << 3);
}

// ---------------- precast fp32 -> bf16 + RoPE table (merged) ----------------
__global__ __launch_bounds__(256) void precast_rope_kernel(
    const float* __restrict__ X, const float* __restrict__ Wq,
    const float* __restrict__ Wk, const float* __restrict__ Wv,
    const float* __restrict__ Wo, const int* __restrict__ tp,
    short* __restrict__ Xb, short* __restrict__ Wqb, short* __restrict__ Wkb,
    short* __restrict__ Wvb, short* __restrict__ Wob,
    float* __restrict__ ct, float* __restrict__ st) {
  int bid = blockIdx.x;
  if (bid < 4096) {
    int i = bid * 256 + threadIdx.x;
    const float* src; short* dst; int off;
    if (i < 524288) { src = X; dst = Xb; off = i; }
    else {
      int k = i - 524288; int w = k >> 17; off = k & 131071;
      src = (w == 0) ? Wq : (w == 1) ? Wk : (w == 2) ? Wv : Wo;
      dst = (w == 0) ? Wqb : (w == 1) ? Wkb : (w == 2) ? Wvb : Wob;
    }
    const float4* p = reinterpret_cast<const float4*>(src) + 2 * (size_t)off;
    float4 a = p[0], b = p[1];
    reinterpret_cast<short8*>(dst)[off] = pack8(a, b);
  } else {
    int idx = (bid - 4096) * 256 + threadIdx.x;
    if (idx >= SEQ * 32) return;
    int s = idx >> 5, i = idx & 31;
    int is64 = (tp[1] == 0);
    int p = is64 ? tp[2 * s] : tp[s];
    float invf = powf(10000.0f, -(2.0f * (float)i) / 64.0f);
    float a = (float)p * invf;
    ct[idx] = cosf(a);
    st[idx] = sinf(a);
  }
}

// ---------------- fused QKV projection + RoPE (round-0 verbatim) ------------
// Best-measured structure (51.4 us): 128x128 tile, 4 waves 2x2, single-
// buffered LDS, 2-barrier K-loop, grid 32x24 -> 3 blocks/CU. DECLARED DONE.
// Q,K stored (B,H,S,64) with RoPE applied; V stored TRANSPOSED (B,H,64,S).
__global__ __launch_bounds__(256) void gemm_qkv_kernel(
    const short* __restrict__ X, const short* __restrict__ Wq,
    const short* __restrict__ Wk, const short* __restrict__ Wv,
    short* __restrict__ Qb, short* __restrict__ Kb, short* __restrict__ Vb,
    const float* __restrict__ ct, const float* __restrict__ st) {
  __shared__ __align__(16) short As[128 * 64];
  __shared__ __align__(16) short Bs[128 * 64];
  const int tm = blockIdx.x;          // 32 (M tiles of 128)
  const int tn = blockIdx.y;          // 24 (N tiles of 128 across 3 matrices)
  const int tid = threadIdx.x;
  const int wave = tid >> 6, lane = tid & 63;
  const int l15 = lane & 15, quad = lane >> 4;
  const int wm = wave >> 1, wn = wave & 1;   // 2x2 wave grid, 64x64 each

  const int mid = tn >> 3;             // 0=Q 1=K 2=V
  const int n0 = (tn & 7) * 128;
  const short* W = (mid == 0) ? Wq : (mid == 1 ? Wk : Wv);
  const short* Abase = X + (size_t)(tm * 128) * DMODEL;
  const short* Bbase = W + (size_t)n0 * DMODEL;

  const int lr = lane >> 3;            // row within 8-row chunk
  const int lc = (lane & 7) ^ lr;      // XOR-permuted source granule

  f32x4 acc[4][4];
#pragma unroll
  for (int mb = 0; mb < 4; mb++)
#pragma unroll
    for (int nb = 0; nb < 4; nb++) acc[mb][nb] = (f32x4){0.f, 0.f, 0.f, 0.f};

  for (int kk = 0; kk < 16; kk++) {
    const short* Ak = Abase + kk * 64;
    const short* Bk = Bbase + kk * 64;
#pragma unroll
    for (int i = 0; i < 4; i++) {
      int R = i * 32 + wave * 8;
      GLDS16(Ak + (size_t)(R + lr) * DMODEL + lc * 8, &As[R * 64 + lane * 8]);
    }
#pragma unroll
    for (int i = 0; i < 4; i++) {
      int R = i * 32 + wave * 8;
      GLDS16(Bk + (size_t)(R + lr) * DMODEL + lc * 8, &Bs[R * 64 + lane * 8]);
    }
    __syncthreads();   // drains vmcnt(0): GLDS complete
#pragma unroll
    for (int kg = 0; kg < 2; kg++) {
      short8 af[4], bf[4];
#pragma unroll
      for (int mb = 0; mb < 4; mb++) {
        int r = wm * 64 + mb * 16 + l15;
        af[mb] = *reinterpret_cast<const short8*>(&As[swz(r, kg * 4 + quad)]);
      }
#pragma unroll
      for (int nb = 0; nb < 4; nb++) {
        int r = wn * 64 + nb * 16 + l15;
        bf[nb] = *reinterpret_cast<const short8*>(&Bs[swz(r, kg * 4 + quad)]);
      }
#pragma unroll
      for (int mb = 0; mb < 4; mb++)
#pragma unroll
        for (int nb = 0; nb < 4; nb++)
          acc[mb][nb] = __builtin_amdgcn_mfma_f32_16x16x32_bf16(af[mb], bf[nb], acc[mb][nb], 0, 0, 0);
    }
    __syncthreads();
  }

  // epilogue
#pragma unroll
  for (int mb = 0; mb < 4; mb++) {
    const int s0g = tm * 128 + wm * 64 + mb * 16 + quad * 4;   // rows s0g..s0g+3
    const int b = s0g >> 11, s = s0g & 2047;
#pragma unroll
    for (int nb = 0; nb < 4; nb++) {
      int nl = n0 + wn * 64 + nb * 16 + l15;
      int h = nl >> 6, dd = nl & 63;
      if (mid == 2) {
        // V: packed b64 transposed store -> Vb[(b,h)][dd][s..s+3]
        unsigned u0 = (unsigned)(unsigned short)f2bf(acc[mb][nb][0]) |
                      ((unsigned)(unsigned short)f2bf(acc[mb][nb][1]) << 16);
        unsigned u1 = (unsigned)(unsigned short)f2bf(acc[mb][nb][2]) |
                      ((unsigned)(unsigned short)f2bf(acc[mb][nb][3]) << 16);
        uint2 pk; pk.x = u0; pk.y = u1;
        *reinterpret_cast<uint2*>(Vb + ((size_t)(b * NHEADS + h) * DKH + dd) * SEQ + s) = pk;
      } else {
#pragma unroll
        for (int reg = 0; reg < 4; reg++) {
          float v = acc[mb][nb][reg];
          float pv = __shfl_xor(v, 1);
          int fi = dd >> 1;
          int sg = s + reg;
          float c = ct[sg * 32 + fi], sn = st[sg * 32 + fi];
          float o = (dd & 1) ? (pv * sn + v * c) : (v * c - pv * sn);
          size_t oi = (((size_t)(b * NHEADS + h)) * SEQ + sg) * DKH + dd;
          ((mid == 0) ? Qb : Kb)[oi] = f2bf(o);
        }
      }
    }
  }
}

// ---------------- flash attention (causal), round 18 ------------------------
// KVBLK=128 via SUB-TILE PAIRS: measured ~370 VALU instrs per 64-key
// iteration vs ~116 irreducible -> per-iter overhead dominates. Process two
// 64-key sub-tiles per stage/barrier pair: Ks[2]/Vs[2] reinterpreted from
// double-buffer to sub-tile pair (same 32KB LDS, 4 blocks/CU KEPT -- the
// lever r8 proved essential). Iterations 16.5 -> 8.75 avg. K staged via
// GLDS16 with pre-swizzled global source (qkv-proven; kreg loads/writes
// deleted). V reg->sigma-write unchanged. Prefetch overlap dropped; latency
// covered by 4-block TLP (qkv-r0 pattern). Tail: wave-uniform t<=qt guard;
// staging never OOB (base+127 <= 2047). Zero-shuffle PV + sigma-V kept.
__global__ __launch_bounds__(256, 4) void attn_kernel(
    const short* __restrict__ Qb, const short* __restrict__ Kb,
    const short* __restrict__ Vtb, short* __restrict__ Ob) {
  __shared__ __align__(16) short Ks[2][64 * 64];   // [sub][key][d]
  __shared__ __align__(16) short Vs[2][64 * 64];   // [sub][dv][sigma-key]

  const int id = blockIdx.x;
  const int x8 = id & 7;               // XCD slot (round-robin dispatch)
  const int c  = (id >> 3) & 31;       // CU slot within XCD
  const int q2 = id >> 8;              // co-residency round (0..3)
  const int bh = x8 * 4 + q2;          // 4 consecutive bh per XCD (L2 local)
  const int qt = (q2 == 0) ? c
               : (q2 == 1) ? (31 - c)
               : (q2 == 2) ? ((c + 16) & 31)
               : ((15 - c) & 31);      // per-CU qt sum = 62 for all c

  const int tid = threadIdx.x;
  const int wave = tid >> 6, lane = tid & 63;
  const int l15 = lane & 15, quad = lane >> 4;
  const int sr0 = tid >> 3, sc = tid & 7;
  const int lr = lane >> 3;            // K GLDS: row within 8-row chunk
  const int lc = (lane & 7) ^ lr;      // K GLDS: pre-swizzled source granule

  // sigma staging constants for V (per-thread):
  const int vga = ((sc >> 2) << 2) + ((sc & 1) << 1);  // 4m + 2p
  const int vh4 = ((sc >> 1) & 1) * 4;                 // slot-half (shorts)

  const short* Qp = Qb + (size_t)bh * SEQ * DKH;
  const short* Kp = Kb + (size_t)bh * SEQ * DKH;
  const short* Vp = Vtb + (size_t)bh * DKH * SEQ;  // rows = dv, cols = s

  // Q fragments: per-lane direct global load (row qt*64+wave*16+l15).
  short8 qf0, qf1;
  {
    const short* qrow = Qp + (size_t)(qt * 64 + wave * 16 + l15) * DKH;
    qf0 = *reinterpret_cast<const short8*>(qrow + quad * 8);
    qf1 = *reinterpret_cast<const short8*>(qrow + (4 + quad) * 8);
  }

  f32x4 accO[4];
#pragma unroll
  for (int i = 0; i < 4; i++) accO[i] = (f32x4){0.f, 0.f, 0.f, 0.f};
  float rs = 0.f;   // partial row-sum for q-row (wave*16+l15), this lane's keys

  const float SCL = 0.125f * 1.44269504089f;   // 1/sqrt(64) * log2(e)
  const float FM = 13.0f;                      // fixed softmax shift (exact)
  const int prow = wave * 16 + l15;            // this lane's q-row (P row)
  const int npairs = (qt + 2) >> 1;

  for (int p = 0; p < npairs; p++) {
    const int base = p * 128;          // key base of this pair
    // --- stage K (128 rows x 64 d) via GLDS, pre-swizzled source ---
#pragma unroll
    for (int i = 0; i < 4; i++) {
      int R = i * 32 + wave * 8;       // 0..127
      GLDS16(Kp + (size_t)(base + R + lr) * DKH + lc * 8,
             &Ks[R >> 6][(R & 63) * 64 + lane * 8]);
    }
    // --- stage V (64 dv x 128 keys) reg -> sigma writes ---
    {
      uint4 vr[2][2];
#pragma unroll
      for (int i = 0; i < 2; i++)
#pragma unroll
        for (int hs = 0; hs < 2; hs++) {
          int r = sr0 + i * 32;
          vr[i][hs] = *reinterpret_cast<const uint4*>(
              Vp + (size_t)r * SEQ + base + hs * 64 + sc * 8);
        }
#pragma unroll
      for (int i = 0; i < 2; i++)
#pragma unroll
        for (int hs = 0; hs < 2; hs++) {
          int r = sr0 + i * 32;
          uint2 lo, hi;
          lo.x = vr[i][hs].x; lo.y = vr[i][hs].y;
          hi.x = vr[i][hs].z; hi.y = vr[i][hs].w;
          *reinterpret_cast<uint2*>(&Vs[hs][swz(r, vga) + vh4]) = lo;
          *reinterpret_cast<uint2*>(&Vs[hs][swz(r, vga + 1) + vh4]) = hi;
        }
    }
    __syncthreads();   // K GLDS + V writes complete for both subs

    // --- compute both sub-tiles ---
#pragma unroll
    for (int s = 0; s < 2; s++) {
      const int t = 2 * p + s;
      if (t <= qt) {
        // S^T = K Q^T : lane holds keys nb*16+quad*4+{0..3}, q-row = prow.
        f32x4 sa[4];
        __builtin_amdgcn_s_setprio(1);
#pragma unroll
        for (int nb = 0; nb < 4; nb++) {
          sa[nb] = (f32x4){0.f, 0.f, 0.f, 0.f};
          int r = nb * 16 + l15;
          short8 kf0 = *reinterpret_cast<const short8*>(&Ks[s][swz(r, quad)]);
          sa[nb] = __builtin_amdgcn_mfma_f32_16x16x32_bf16(kf0, qf0, sa[nb], 0, 0, 0);
          short8 kf1 = *reinterpret_cast<const short8*>(&Ks[s][swz(r, 4 + quad)]);
          sa[nb] = __builtin_amdgcn_mfma_f32_16x16x32_bf16(kf1, qf1, sa[nb], 0, 0, 0);
        }
        __builtin_amdgcn_s_setprio(0);

        const bool diag = (t == qt);
        unsigned pu[4], pw[4];
#pragma unroll
        for (int nb = 0; nb < 4; nb++) {
          float p0 = exp2f(sa[nb][0] * SCL - FM);
          float p1 = exp2f(sa[nb][1] * SCL - FM);
          float p2 = exp2f(sa[nb][2] * SCL - FM);
          float p3 = exp2f(sa[nb][3] * SCL - FM);
          if (diag) {
            int kbase = nb * 16 + quad * 4;
            if (kbase + 0 > prow) p0 = 0.f;
            if (kbase + 1 > prow) p1 = 0.f;
            if (kbase + 2 > prow) p2 = 0.f;
            if (kbase + 3 > prow) p3 = 0.f;
          }
          rs += (p0 + p1) + (p2 + p3);
          pu[nb] = cvtpk(p0, p1);
          pw[nb] = cvtpk(p2, p3);
        }

        // O += P V, zero-shuffle (sigma key order both sides).
        short8 pf0, pf1;
        {
          unsigned* w0 = reinterpret_cast<unsigned*>(&pf0);
          w0[0] = pu[0]; w0[1] = pw[0]; w0[2] = pu[1]; w0[3] = pw[1];
          unsigned* w1 = reinterpret_cast<unsigned*>(&pf1);
          w1[0] = pu[2]; w1[1] = pw[2]; w1[2] = pu[3]; w1[3] = pw[3];
        }
        __builtin_amdgcn_s_setprio(1);
#pragma unroll
        for (int db = 0; db < 4; db++) {
          int dv = db * 16 + l15;
          short8 vf0 = *reinterpret_cast<const short8*>(&Vs[s][swz(dv, quad)]);
          accO[db] = __builtin_amdgcn_mfma_f32_16x16x32_bf16(pf0, vf0, accO[db], 0, 0, 0);
          short8 vf1 = *reinterpret_cast<const short8*>(&Vs[s][swz(dv, 4 + quad)]);
          accO[db] = __builtin_amdgcn_mfma_f32_16x16x32_bf16(pf1, vf1, accO[db], 0, 0, 0);
        }
        __builtin_amdgcn_s_setprio(0);
      }
    }
    __syncthreads();   // all waves done reading Ks/Vs before next stage
  }

  // reduce rs across the 4 quads sharing each l15 (full row sum)
  float t = rs;
  t += __shfl_xor(t, 16);
  t += __shfl_xor(t, 32);
  // accO rows are qrow = quad*4+reg; fetch lrow from lane l15 = quad*4+reg
  float lv[4];
#pragma unroll
  for (int reg = 0; reg < 4; reg++) lv[reg] = __shfl(t, quad * 4 + reg);

  // write (B,S,1024) bf16
  int b = bh >> 4, h = bh & 15;
#pragma unroll
  for (int db = 0; db < 4; db++)
#pragma unroll
    for (int reg = 0; reg < 4; reg++) {
      int s = qt * 64 + wave * 16 + quad * 4 + reg;
      int dv = db * 16 + l15;
      float o = accO[db][reg] / lv[reg];
      Ob[((size_t)(b * SEQ + s)) * DMODEL + h * DKH + dv] = f2bf(o);
    }
}

// ---------------- output projection (round-0 verbatim) ----------------------
// REVERTED: BK=128 double-stage regressed ~15-20us (2 blocks/CU, TLP loss >
// drain savings -- same lesson as r1/r8). 128x64 tile + GLDS, 24KB LDS.
__global__ __launch_bounds__(256) void gemm_out_kernel(
    const short* __restrict__ X, const short* __restrict__ Wo, float* __restrict__ Out) {
  __shared__ __align__(16) short As[128 * 64];
  __shared__ __align__(16) short Bs[64 * 64];
  const int tm = blockIdx.x;   // 32 (M tiles of 128)
  const int tn = blockIdx.y;   // 16 (N tiles of 64)
  const int tid = threadIdx.x;
  const int wave = tid >> 6, lane = tid & 63;
  const int l15 = lane & 15, quad = lane >> 4;
  const int wm = wave >> 1, wn = wave & 1;   // wave tile 64M x 32N

  const short* Abase = X + (size_t)(tm * 128) * DMODEL;
  const short* Bbase = Wo + (size_t)(tn * 64) * DMODEL;

  const int lr = lane >> 3;
  const int lc = (lane & 7) ^ lr;

  f32x4 acc[4][2];
#pragma unroll
  for (int mb = 0; mb < 4; mb++)
#pragma unroll
    for (int nb = 0; nb < 2; nb++) acc[mb][nb] = (f32x4){0.f, 0.f, 0.f, 0.f};

  for (int kk = 0; kk < 16; kk++) {
    const short* Ak = Abase + kk * 64;
    const short* Bk = Bbase + kk * 64;
#pragma unroll
    for (int i = 0; i < 4; i++) {
      int R = i * 32 + wave * 8;
      GLDS16(Ak + (size_t)(R + lr) * DMODEL + lc * 8, &As[R * 64 + lane * 8]);
    }
#pragma unroll
    for (int i = 0; i < 2; i++) {
      int R = i * 32 + wave * 8;
      GLDS16(Bk + (size_t)(R + lr) * DMODEL + lc * 8, &Bs[R * 64 + lane * 8]);
    }
    __syncthreads();
#pragma unroll
    for (int kg = 0; kg < 2; kg++) {
      short8 af[4], bf[2];
#pragma unroll
      for (int mb = 0; mb < 4; mb++) {
        int r = wm * 64 + mb * 16 + l15;
        af[mb] = *reinterpret_cast<const short8*>(&As[swz(r, kg * 4 + quad)]);
      }
#pragma unroll
      for (int nb = 0; nb < 2; nb++) {
        int r = wn * 32 + nb * 16 + l15;
        bf[nb] = *reinterpret_cast<const short8*>(&Bs[swz(r, kg * 4 + quad)]);
      }
#pragma unroll
      for (int mb = 0; mb < 4; mb++)
#pragma unroll
        for (int nb = 0; nb < 2; nb++)
          acc[mb][nb] = __builtin_amdgcn_mfma_f32_16x16x32_bf16(af[mb], bf[nb], acc[mb][nb], 0, 0, 0);
    }
    __syncthreads();
  }
#pragma unroll
  for (int mb = 0; mb < 4; mb++)
#pragma unroll
    for (int nb = 0; nb < 2; nb++)
#pragma unroll
      for (int reg = 0; reg < 4; reg++) {
        int rg = tm * 128 + wm * 64 + mb * 16 + quad * 4 + reg;
        int col = tn * 64 + wn * 32 + nb * 16 + l15;
        Out[(size_t)rg * DMODEL + col] = acc[mb][nb][reg];
      }
}

extern "C" void kernel_launch(void* const* d_in, const int* in_sizes, int n_in,
                              void* d_out, int out_size, void* d_ws, size_t ws_size,
                              hipStream_t stream) {
  (void)in_sizes; (void)n_in; (void)out_size; (void)ws_size;
  const float* X  = (const float*)d_in[0];
  const int*   tp = (const int*)d_in[1];
  const float* Wq = (const float*)d_in[2];
  const float* Wk = (const float*)d_in[3];
  const float* Wv = (const float*)d_in[4];
  const float* Wo = (const float*)d_in[5];
  float* Out = (float*)d_out;

  short* Qb  = (short*)d_ws;           // 4M shorts each
  short* Kb  = Qb + 4194304;
  short* Vb  = Kb + 4194304;           // holds V^T (B,H,D,S)
  short* Ab  = Vb + 4194304;
  short* Xb  = Ab + 4194304;           // 4M
  short* Wqb = Xb + 4194304;           // 1M each
  short* Wkb = Wqb + 1048576;
  short* Wvb = Wkb + 1048576;
  short* Wob = Wvb + 1048576;
  float* ct  = (float*)(Wob + 1048576);
  float* st  = ct + SEQ * 32;

  precast_rope_kernel<<<dim3(4352), dim3(256), 0, stream>>>(
      X, Wq, Wk, Wv, Wo, tp, Xb, Wqb, Wkb, Wvb, Wob, ct, st);
  gemm_qkv_kernel<<<dim3(32, 24), dim3(256), 0, stream>>>(Xb, Wqb, Wkb, Wvb,
                                                          Qb, Kb, Vb, ct, st);
  attn_kernel<<<dim3(1024), dim3(256), 0, stream>>>(Qb, Kb, Vb, Ab);
  gemm_out_kernel<<<dim3(32, 16), dim3(256), 0, stream>>>(Ab, Wob, Out);
}